// Round 8
// baseline (435.514 us; speedup 1.0000x reference)
//
#include <hip/hip_runtime.h>
#include <cstdint>

#define H_ 128
#define W_ 128
#define HW 16384

typedef _Float16 f16x8 __attribute__((ext_vector_type(8)));
typedef _Float16 f16x4 __attribute__((ext_vector_type(4)));
typedef _Float16 f16x2 __attribute__((ext_vector_type(2)));
typedef float f32x4 __attribute__((ext_vector_type(4)));

// halo layout: [b][h'=0..129][w'=0..129][C], interior at h'=h+1,w'=w+1, halo zero
#define EF_SZ  25958400ULL   // 4*130*130*192*2
#define T_SZ   8652800ULL    // 4*130*130*64*2

// ---------------------------------------------------------------------------
// All weight preps + input transposes in ONE launch (branch ladder on blockIdx).
// ---------------------------------------------------------------------------
__global__ __launch_bounds__(256)
void prep_all(const float* __restrict__ wd, const float* __restrict__ w1,
              const float* __restrict__ w2, const float* __restrict__ w3,
              const float* __restrict__ w4, const float* __restrict__ x,
              const float* __restrict__ ef,
              _Float16* __restrict__ wp, _Float16* __restrict__ A1,
              _Float16* __restrict__ A2, _Float16* __restrict__ A3,
              _Float16* __restrict__ A4, _Float16* __restrict__ xt,
              _Float16* __restrict__ ef_t) {
    __shared__ __align__(16) _Float16 t[128 * 200];
    const int bx  = blockIdx.x;
    const int tid = threadIdx.x;
    if (bx < 384) {                          // deform weight -> Wp[g][o][kc96]
        int i = bx * 256 + tid;
        int kc = i % 96;
        int go = i / 96;
        int o = go & 63, g = go >> 6;
        float v = 0.f;
        if (kc < 72) { int k = kc >> 3, c = kc & 7; v = wd[(o * 128 + g * 8 + c) * 9 + k]; }
        wp[i] = (_Float16)v;
    } else if (bx < 2256) {                  // conv A layouts
        const float* w; _Float16* Ap; int CIN, COUT, COpad, base;
        if (bx < 816)       { w = w1; Ap = A1; CIN = 192; COUT = 64;  COpad = 64;  base = 384; }
        else if (bx < 960)  { w = w2; Ap = A2; CIN = 64;  COUT = 64;  COpad = 64;  base = 816; }
        else if (bx < 1104) { w = w3; Ap = A3; CIN = 64;  COUT = 64;  COpad = 64;  base = 960; }
        else                { w = w4; Ap = A4; CIN = 64;  COUT = 432; COpad = 512; base = 1104; }
        int i = (bx - base) * 256 + tid;
        int kb = i / (COpad * 8);
        int rem = i - kb * (COpad * 8);
        int co = rem >> 3, j = rem & 7;
        int k = kb * 8 + j;
        int s = k / CIN;
        int ci = k - s * CIN;
        int kh = s / 3, kw = s % 3;
        float v = (co < COUT) ? w[((size_t)co * CIN + ci) * 9 + kh * 3 + kw] : 0.f;
        Ap[i] = (_Float16)v;
    } else if (bx < 6352) {                  // x -> xt[b][g][px][c8] fp16
        int i = (bx - 2256) * 256 + tid;
        int px = i & 16383;
        int g  = (i >> 14) & 15;
        int b  = i >> 18;
        const float* xp = x + ((size_t)(b * 128 + g * 8) * HW) + px;
        f16x8 v;
        #pragma unroll
        for (int c = 0; c < 8; ++c) v[c] = (_Float16)xp[c * HW];
        *(f16x8*)(xt + (size_t)i * 8) = v;
    } else {                                 // extra_feat NCHW -> halo NHWC fp16
        int bb = bx - 6352;
        int b = bb >> 7, h = bb & 127;
        for (int i = tid; i < 192 * 128; i += 256) {
            int c = i >> 7, w = i & 127;
            t[w * 200 + c] = (_Float16)ef[((size_t)(b * 192 + c) * 128 + h) * 128 + w];
        }
        __syncthreads();
        _Float16* ob = ef_t + ((size_t)((b * 130 + h + 1) * 130) + 1) * 192;
        for (int i = tid; i < 128 * 24; i += 256) {
            int px = i / 24, c8 = i % 24;
            *(f16x8*)(ob + px * 192 + c8 * 8) = *(const f16x8*)(t + px * 200 + c8 * 8);
        }
    }
}

// ---------------------------------------------------------------------------
// Barrier-free MFMA implicit-GEMM 3x3 conv. Input: zero-halo NHWC fp16
// [b][130][130][CIN]. B-fragments loaded DIRECTLY from global (wave = 16 px
// x 4 c8-quads -> sixteen full 64B lines per load; L1/L2-resident rows).
// No LDS, no __syncthreads. ACT 1 = lrelu -> halo NHWC fp16 (64 co).
// ACT 2 = conv4 epilogue -> packed off2 (dy,dx) + msk planes.
// ---------------------------------------------------------------------------
template<int CIN, int COpad, int NWM, int NWN, int MT, int NT, int ACT>
__global__ __launch_bounds__(256)
void conv_direct(const _Float16* __restrict__ in, const _Float16* __restrict__ Ap,
                 const float* __restrict__ bias, void* __restrict__ outp,
                 _Float16* __restrict__ mskp) {
    static_assert(NWM * NWN == 4 && NWN * NT * 16 == 128, "tiling");
    const int tid  = threadIdx.x;
    const int b    = blockIdx.x >> 7;
    const int h    = blockIdx.x & 127;
    const int cogB = blockIdx.y * (NWM * MT * 16);
    const int wv   = tid >> 6;
    const int wv_m = wv / NWN;
    const int wv_n = wv % NWN;
    const int lane = tid & 63;
    const int quad = lane >> 4;
    const int l16  = lane & 15;

    f32x4 acc[MT][NT];
    #pragma unroll
    for (int mt = 0; mt < MT; ++mt)
        #pragma unroll
        for (int nt = 0; nt < NT; ++nt) acc[mt][nt] = (f32x4){0.f, 0.f, 0.f, 0.f};

    #pragma unroll
    for (int kh = 0; kh < 3; ++kh) {
        const _Float16* rowp = in + ((size_t)((b * 130 + h + kh) * 130)) * CIN;
        #pragma unroll
        for (int kwi = 0; kwi < 3; ++kwi) {
            #pragma unroll
            for (int ci32 = 0; ci32 < CIN / 32; ++ci32) {
                const int kb0 = (kh * 3 + kwi) * (CIN / 8) + ci32 * 4;
                f16x8 aF[MT];
                #pragma unroll
                for (int mt = 0; mt < MT; ++mt) {
                    int co_m = cogB + (wv_m * MT + mt) * 16 + l16;
                    aF[mt] = *(const f16x8*)(Ap + ((size_t)(kb0 + quad) * COpad + co_m) * 8);
                }
                #pragma unroll
                for (int nt = 0; nt < NT; ++nt) {
                    int n = (wv_n * NT + nt) * 16 + l16;
                    f16x8 bF = *(const f16x8*)(rowp + (size_t)(n + kwi) * CIN + (ci32 * 4 + quad) * 8);
                    #pragma unroll
                    for (int mt = 0; mt < MT; ++mt)
                        acc[mt][nt] = __builtin_amdgcn_mfma_f32_16x16x32_f16(aF[mt], bF, acc[mt][nt], 0, 0, 0);
                }
            }
        }
    }

    if (ACT == 1) {
        _Float16* ob = (_Float16*)outp + ((size_t)((b * 130 + h + 1) * 130) + 1) * 64;
        #pragma unroll
        for (int mt = 0; mt < MT; ++mt) {
            int co_b = (wv_m * MT + mt) * 16 + quad * 4;
            #pragma unroll
            for (int nt = 0; nt < NT; ++nt) {
                int px = (wv_n * NT + nt) * 16 + l16;
                f16x4 sv;
                #pragma unroll
                for (int r = 0; r < 4; ++r) {
                    float v = acc[mt][nt][r] + bias[co_b + r];
                    v = v > 0.f ? v : 0.1f * v;
                    sv[r] = (_Float16)v;
                }
                *(f16x4*)(ob + (size_t)px * 64 + co_b) = sv;
            }
        }
    } else {
        _Float16* off2 = (_Float16*)outp;
        #pragma unroll
        for (int mt = 0; mt < MT; ++mt) {
            int co_base = cogB + (wv_m * MT + mt) * 16 + quad * 4;   // even
            #pragma unroll
            for (int r2 = 0; r2 < 2; ++r2) {
                int co0 = co_base + 2 * r2;
                if (co0 < 288) {             // offset pair (dy co0, dx co0+1)
                    int g = co0 / 18;
                    int k = (co0 - g * 18) >> 1;
                    float bv0 = bias[co0], bv1 = bias[co0 + 1];
                    #pragma unroll
                    for (int nt = 0; nt < NT; ++nt) {
                        int px = (wv_n * NT + nt) * 16 + l16;
                        float v0 = acc[mt][nt][2 * r2]     + bv0;
                        float v1 = acc[mt][nt][2 * r2 + 1] + bv1;
                        float e0 = __expf(2.f * v0);
                        float e1 = __expf(2.f * v1);
                        f16x2 ov;
                        ov[0] = (_Float16)(10.f * (1.f - 2.f / (e0 + 1.f)));
                        ov[1] = (_Float16)(10.f * (1.f - 2.f / (e1 + 1.f)));
                        *(f16x2*)(off2 + (((size_t)(b * 16 + g) * 9 + k) * HW + h * 128 + px) * 2) = ov;
                    }
                } else if (co0 < 432) {      // two mask channels
                    #pragma unroll
                    for (int j = 0; j < 2; ++j) {
                        int co = co0 + j;
                        int mm = co - 288;
                        int g = mm / 9;
                        int k = mm - g * 9;
                        float bv = bias[co];
                        #pragma unroll
                        for (int nt = 0; nt < NT; ++nt) {
                            int px = (wv_n * NT + nt) * 16 + l16;
                            float v = acc[mt][nt][2 * r2 + j] + bv;
                            v = 1.f / (1.f + __expf(-v));
                            mskp[((size_t)(b * 16 + g) * 9 + k) * HW + h * 128 + px] = (_Float16)v;
                        }
                    }
                }
            }
        }
    }
}

// ---------------------------------------------------------------------------
// Fused deformable conv, two teams. Block = (b, hrow), 512 threads (8 waves).
// Team 0 (waves 0-3) handles groups 0-7, team 1 (waves 4-7) groups 8-15;
// each team owns a 32 KB V buffer (128px x 96kc fp16, swizzle k^(px&15)).
// After 8 rounds, team 1 dumps fp32 acc to LDS, team 0 adds + bias and
// writes FINAL fp32 output. No partial buffer, no reduce kernel.
// ---------------------------------------------------------------------------
__global__ __launch_bounds__(512)
void deform_mfma(const _Float16* __restrict__ xt, const _Float16* __restrict__ off2,
                 const _Float16* __restrict__ msk, const _Float16* __restrict__ wp,
                 const float* __restrict__ bias, float* __restrict__ out) {
    __shared__ __align__(16) char vlds[2][128 * 256];   // 64 KB
    const int tid  = threadIdx.x;
    const int b    = blockIdx.x >> 7;
    const int hrow = blockIdx.x & 127;
    const int wv   = tid >> 6;
    const int team = wv >> 2;          // wave-uniform
    const int mt   = wv & 3;           // m-tile (16 co)
    const int lane = tid & 63;
    const int quad = lane >> 4;
    const int l16  = lane & 15;

    const int ttid = tid & 255;        // within-team thread
    const int px   = ttid & 127;       // pixel (V row)
    const int ks   = ttid >> 7;        // k parity

    {
        f32x4 z = (f32x4){0.f, 0.f, 0.f, 0.f};
        for (int i = tid; i < 4096; i += 512) ((f32x4*)vlds)[i] = z;
    }

    const _Float16* o2b = off2 + (size_t)b * 16 * 9 * HW * 2;
    const _Float16* mb  = msk  + (size_t)b * 16 * 9 * HW;
    const int pxg = hrow * 128 + px;
    char* vbuf = vlds[team];

    f32x4 acc[8];
    #pragma unroll
    for (int nt = 0; nt < 8; ++nt) acc[nt] = (f32x4){0.f, 0.f, 0.f, 0.f};

    #pragma unroll 1
    for (int gl = 0; gl < 8; ++gl) {
        const int g = team * 8 + gl;
        const _Float16* xg = xt + ((size_t)(b * 16 + g) * HW) * 8;
        __syncthreads();               // prior round's V fully consumed
        // batched offset/mask loads, then dependent gathers
        float dyv[5], dxv[5], mv[5];
        #pragma unroll
        for (int i = 0; i < 5; ++i) {
            int k = ks + 2 * i;
            if (k < 9) {
                f16x2 od = *(const f16x2*)(o2b + ((size_t)(g * 9 + k) * HW + pxg) * 2);
                dyv[i] = (float)od[0];
                dxv[i] = (float)od[1];
                mv[i]  = (float)mb[(size_t)(g * 9 + k) * HW + pxg];
            }
        }
        #pragma unroll
        for (int i = 0; i < 5; ++i) {
            int k = ks + 2 * i;
            if (k < 9) {
                float py  = (float)(hrow - 1 + k / 3) + dyv[i];
                float pxf = (float)(px - 1 + k % 3) + dxv[i];
                float y0f = floorf(py), x0f = floorf(pxf);
                float ly = py - y0f, lx = pxf - x0f;
                int y0 = (int)y0f, x0 = (int)x0f;
                int y1 = y0 + 1,  x1 = x0 + 1;
                float vy0 = ((unsigned)y0 < 128u) ? 1.f : 0.f;
                float vy1 = ((unsigned)y1 < 128u) ? 1.f : 0.f;
                float vx0 = ((unsigned)x0 < 128u) ? 1.f : 0.f;
                float vx1 = ((unsigned)x1 < 128u) ? 1.f : 0.f;
                float m = mv[i];
                float w00 = (1.f - ly) * (1.f - lx) * vy0 * vx0 * m;
                float w01 = (1.f - ly) * lx         * vy0 * vx1 * m;
                float w10 = ly * (1.f - lx)         * vy1 * vx0 * m;
                float w11 = ly * lx                 * vy1 * vx1 * m;
                int yc0 = min(max(y0, 0), 127), yc1 = min(max(y1, 0), 127);
                int xc0 = min(max(x0, 0), 127), xc1 = min(max(x1, 0), 127);
                f16x8 c00 = *(const f16x8*)(xg + (yc0 * W_ + xc0) * 8);
                f16x8 c01 = *(const f16x8*)(xg + (yc0 * W_ + xc1) * 8);
                f16x8 c10 = *(const f16x8*)(xg + (yc1 * W_ + xc0) * 8);
                f16x8 c11 = *(const f16x8*)(xg + (yc1 * W_ + xc1) * 8);
                _Float16 h00 = (_Float16)w00, h01 = (_Float16)w01;
                _Float16 h10 = (_Float16)w10, h11 = (_Float16)w11;
                f16x8 vv = c00 * h00 + c01 * h01 + c10 * h10 + c11 * h11;
                int chunk = k ^ (px & 15);
                *(f16x8*)(vbuf + px * 256 + chunk * 16) = vv;
            }
        }
        __syncthreads();               // V visible
        f16x8 aF[3];
        const _Float16* wg = wp + ((size_t)(g * 64 + mt * 16 + l16)) * 96 + quad * 8;
        #pragma unroll
        for (int s = 0; s < 3; ++s) aF[s] = *(const f16x8*)(wg + s * 32);
        #pragma unroll
        for (int nt = 0; nt < 8; ++nt) {
            int row = nt * 16 + l16;
            int sw  = row & 15;
            #pragma unroll
            for (int s = 0; s < 3; ++s) {
                f16x8 bF = *(const f16x8*)(vbuf + row * 256 + (((s << 2) + quad) ^ sw) * 16);
                acc[nt] = __builtin_amdgcn_mfma_f32_16x16x32_f16(aF[s], bF, acc[nt], 0, 0, 0);
            }
        }
    }

    // ---- cross-team reduce + final write ----
    __syncthreads();
    float* vf = (float*)(vlds[1]);     // 64co x 128px fp32 = 32 KB
    if (team == 1) {
        #pragma unroll
        for (int r = 0; r < 4; ++r) {
            int o = mt * 16 + quad * 4 + r;
            #pragma unroll
            for (int nt = 0; nt < 8; ++nt)
                vf[o * 128 + nt * 16 + l16] = acc[nt][r];
        }
    }
    __syncthreads();
    if (team == 0) {
        #pragma unroll
        for (int r = 0; r < 4; ++r) {
            int o = mt * 16 + quad * 4 + r;
            float bv = bias[o];
            float* po = out + ((size_t)(b * 64 + o)) * HW + hrow * 128 + l16;
            #pragma unroll
            for (int nt = 0; nt < 8; ++nt)
                po[nt * 16] = acc[nt][r] + vf[o * 128 + nt * 16 + l16] + bv;
        }
    }
}

// ---------------------------------------------------------------------------
extern "C" void kernel_launch(void* const* d_in, const int* in_sizes, int n_in,
                              void* d_out, int out_size, void* d_ws, size_t ws_size,
                              hipStream_t stream) {
    const float* x  = (const float*)d_in[0];
    const float* ef = (const float*)d_in[1];
    const float* w1 = (const float*)d_in[2];
    const float* b1 = (const float*)d_in[3];
    const float* w2 = (const float*)d_in[4];
    const float* b2 = (const float*)d_in[5];
    const float* w3 = (const float*)d_in[6];
    const float* b3 = (const float*)d_in[7];
    const float* w4 = (const float*)d_in[8];
    const float* b4 = (const float*)d_in[9];
    const float* wd = (const float*)d_in[10];
    const float* bd = (const float*)d_in[11];
    float* out = (float*)d_out;

    char* ws = (char*)d_ws;
    _Float16* ef_t = (_Float16*)(ws);                     // 25,958,400 B (halo)
    _Float16* tA   = (_Float16*)(ws + 25958400);          //  8,652,800 B (halo)
    _Float16* tB   = (_Float16*)(ws + 34611200);          //  8,652,800 B (halo)
    _Float16* off2 = (_Float16*)(ws + 43264000);          // 37,748,736 B
    _Float16* mskb = (_Float16*)(ws + 81012736);          // 18,874,368 B
    _Float16* wpd  = (_Float16*)(ws + 99887104);          //    196,608 B
    _Float16* A1   = (_Float16*)(ws + 100083712);         //    221,184 B
    _Float16* A2   = (_Float16*)(ws + 100304896);         //     73,728 B
    _Float16* A3   = (_Float16*)(ws + 100378624);         //     73,728 B
    _Float16* A4   = (_Float16*)(ws + 100452352);         //    589,824 B
    _Float16* xtb  = (_Float16*)(ws + 101042176);         // 16,777,216 B -> ends 117,819,392

    // zero the halo buffers (re-poisoned 0xAA before every call)
    hipMemsetAsync(ef_t, 0, EF_SZ, stream);
    hipMemsetAsync(tA,   0, T_SZ,  stream);
    hipMemsetAsync(tB,   0, T_SZ,  stream);

    prep_all<<<6864, 256, 0, stream>>>(wd, w1, w2, w3, w4, x, ef,
                                       wpd, A1, A2, A3, A4, xtb, ef_t);

    conv_direct<192, 64, 2, 2, 2, 4, 1><<<dim3(512, 1), 256, 0, stream>>>(ef_t, A1, b1, tA, nullptr);
    conv_direct< 64, 64, 2, 2, 2, 4, 1><<<dim3(512, 1), 256, 0, stream>>>(tA, A2, b2, tB, nullptr);
    conv_direct< 64, 64, 2, 2, 2, 4, 1><<<dim3(512, 1), 256, 0, stream>>>(tB, A3, b3, tA, nullptr);
    conv_direct< 64, 512, 2, 2, 4, 4, 2><<<dim3(512, 4), 256, 0, stream>>>(tA, A4, b4, off2, mskb);

    deform_mfma<<<512, 512, 0, stream>>>(xtb, off2, mskb, wpd, bd, out);
}